// Round 1
// baseline (41501.938 us; speedup 1.0000x reference)
//
#include <hip/hip_runtime.h>

#define BB 256
#define TT 1024
#define DDIM 6
#define HH 256

// grid: 256 blocks = 4 batch-groups (bg = blk & 3) x 64 gate-groups (gg = blk >> 2)
// each WG owns hidden units [gg*4, gg*4+4) of BOTH layers, batch rows [bg*64, bg*64+64)
// block: 256 threads = 64 batch rows (b_l = tid >> 2) x 4 units (ul = tid & 3)
// ws layout: flags[256] @0 (1KB) | h1g[2][256][256] f32 @1024 | h2g[2][256][256] @525312

__device__ __forceinline__ float sigf(float x) {
    return __builtin_amdgcn_rcpf(1.0f + __expf(-x));
}
__device__ __forceinline__ float tanhf_fast(float x) {
    // tanh(x) = 2/(1+exp(-2x)) - 1 ; saturates gracefully at +-1
    return fmaf(2.0f, __builtin_amdgcn_rcpf(1.0f + __expf(-2.0f * x)), -1.0f);
}

// barrier among the 64 WGs of one batch-group (blocks with blockIdx%4 == bg).
// release: __syncthreads drains vmcnt (stores in local L2), one thread does the
// agent fence (L2 writeback to coherent point) then an agent release store of
// its flag. acquire: wave0 polls all 64 flags (relaxed agent loads), then one
// agent fence (cache invalidate) before anyone reads.
__device__ __forceinline__ void group_barrier(int* flags, int bg, int token) {
    __syncthreads();
    if (threadIdx.x == 0) {
        __threadfence();
        __hip_atomic_store(&flags[blockIdx.x], token, __ATOMIC_RELEASE, __HIP_MEMORY_SCOPE_AGENT);
    }
    if (threadIdx.x < 64) {
        while (__hip_atomic_load(&flags[bg + 4 * (int)threadIdx.x], __ATOMIC_RELAXED,
                                 __HIP_MEMORY_SCOPE_AGENT) < token) {
            __builtin_amdgcn_s_sleep(1);
        }
        __threadfence();
    }
    __syncthreads();
}

// 64 float4 quads of one h-stream (global, 4-lane broadcast) against 4 LDS
// weight rows (16-lane broadcast, bank-quad disjoint across ul).
__device__ __forceinline__ void dot64(const float4* __restrict__ hp,
                                      const float4* __restrict__ w0,
                                      const float4* __restrict__ w1,
                                      const float4* __restrict__ w2,
                                      const float4* __restrict__ w3,
                                      float& a0, float& a1, float& a2, float& a3) {
    #pragma unroll 16
    for (int k = 0; k < 64; ++k) {
        const float4 h  = hp[k];
        const float4 q0 = w0[k];
        const float4 q1 = w1[k];
        const float4 q2 = w2[k];
        const float4 q3 = w3[k];
        a0 = fmaf(h.x, q0.x, a0); a0 = fmaf(h.y, q0.y, a0);
        a0 = fmaf(h.z, q0.z, a0); a0 = fmaf(h.w, q0.w, a0);
        a1 = fmaf(h.x, q1.x, a1); a1 = fmaf(h.y, q1.y, a1);
        a1 = fmaf(h.z, q1.z, a1); a1 = fmaf(h.w, q1.w, a1);
        a2 = fmaf(h.x, q2.x, a2); a2 = fmaf(h.y, q2.y, a2);
        a2 = fmaf(h.z, q2.z, a2); a2 = fmaf(h.w, q2.w, a2);
        a3 = fmaf(h.x, q3.x, a3); a3 = fmaf(h.y, q3.y, a3);
        a3 = fmaf(h.z, q3.z, a3); a3 = fmaf(h.w, q3.w, a3);
    }
}

__device__ __forceinline__ void emit_out(const float* __restrict__ h2row,
                                         const float (*Wo)[256],
                                         float (*redsc)[8],
                                         const float* __restrict__ b_out,
                                         float* __restrict__ op, int tid) {
    const float hval = h2row[tid];
    float p0 = Wo[0][tid] * hval;
    float p1 = Wo[1][tid] * hval;
    float p2 = Wo[2][tid] * hval;
    float p3 = Wo[3][tid] * hval;
    float p4 = Wo[4][tid] * hval;
    float p5 = Wo[5][tid] * hval;
    #pragma unroll
    for (int off = 1; off < 64; off <<= 1) {
        p0 += __shfl_xor(p0, off);
        p1 += __shfl_xor(p1, off);
        p2 += __shfl_xor(p2, off);
        p3 += __shfl_xor(p3, off);
        p4 += __shfl_xor(p4, off);
        p5 += __shfl_xor(p5, off);
    }
    const int wid = tid >> 6;
    if ((tid & 63) == 0) {
        redsc[wid][0] = p0; redsc[wid][1] = p1; redsc[wid][2] = p2;
        redsc[wid][3] = p3; redsc[wid][4] = p4; redsc[wid][5] = p5;
    }
    __syncthreads();
    if (tid < 6) {
        op[tid] = redsc[0][tid] + redsc[1][tid] + redsc[2][tid] + redsc[3][tid] + b_out[tid];
    }
}

__global__ __launch_bounds__(256) void lstm_persist(
    const float* __restrict__ x,
    const float* __restrict__ W_ih1, const float* __restrict__ W_hh1,
    const float* __restrict__ b_ih1, const float* __restrict__ b_hh1,
    const float* __restrict__ W_ih2, const float* __restrict__ W_hh2,
    const float* __restrict__ b_ih2, const float* __restrict__ b_hh2,
    const float* __restrict__ W_out, const float* __restrict__ b_out,
    float* __restrict__ out,
    int* __restrict__ flags, float* __restrict__ h1g, float* __restrict__ h2g)
{
    // rl = g*4 + ul  (g = gate i/f/g/o, ul = unit-sub). pads 260/516/8 keep the
    // 4 ul-lanes on disjoint bank quads (stride mod 32 = 4) and 16B alignment.
    __shared__ float L1w[16][260];   // cols 0..255 = W_hh1 row
    __shared__ float Wx1[16][8];     // cols 0..5   = W_ih1 row (x part)
    __shared__ float L2w[16][516];   // cols 0..255 = W_ih2 (h1 in), 256..511 = W_hh2 (h2 in)
    __shared__ float Wo[6][256];
    __shared__ float redsc[4][8];

    const int tid = threadIdx.x;
    const int bg  = blockIdx.x & 3;
    const int gg  = blockIdx.x >> 2;
    const int b_l = tid >> 2;
    const int ul  = tid & 3;
    const int unit = (gg << 2) + ul;       // hidden unit this thread owns
    const int b    = (bg << 6) + b_l;      // global batch row
    const int ro   = (bg << 6) + gg;       // batch row whose `out` this WG emits

    // ---- one-time weight staging ----
    for (int rl = 0; rl < 16; ++rl) {
        const int g  = rl >> 2;
        const int u2 = rl & 3;
        const int gr = g * HH + (gg << 2) + u2;   // global gate row
        L1w[rl][tid]       = W_hh1[gr * HH + tid];
        if (tid < DDIM) Wx1[rl][tid] = W_ih1[gr * DDIM + tid];
        L2w[rl][tid]       = W_ih2[gr * HH + tid];
        L2w[rl][256 + tid] = W_hh2[gr * HH + tid];
    }
    for (int i = tid; i < 6 * 256; i += 256) Wo[i >> 8][i & 255] = W_out[i];

    float b1a[4], b2a[4];
    #pragma unroll
    for (int g = 0; g < 4; ++g) {
        const int gr = g * HH + unit;
        b1a[g] = b_ih1[gr] + b_hh1[gr];
        b2a[g] = b_ih2[gr] + b_hh2[gr];
    }
    __syncthreads();

    const float4* w10 = (const float4*)&L1w[ul][0];
    const float4* w11 = (const float4*)&L1w[4 + ul][0];
    const float4* w12 = (const float4*)&L1w[8 + ul][0];
    const float4* w13 = (const float4*)&L1w[12 + ul][0];
    const float4* w20 = (const float4*)&L2w[ul][0];
    const float4* w21 = (const float4*)&L2w[4 + ul][0];
    const float4* w22 = (const float4*)&L2w[8 + ul][0];
    const float4* w23 = (const float4*)&L2w[12 + ul][0];

    float c1 = 0.0f, c2 = 0.0f;

    #pragma unroll 1
    for (int t = 0; t < TT; ++t) {
        const int cur = t & 1, prv = cur ^ 1;

        // ---- layer 1: gates for (b, unit) ----
        const float* xp = x + b * (TT * DDIM) + t * DDIM;   // issue x loads early
        const float xv0 = xp[0], xv1 = xp[1], xv2 = xp[2];
        const float xv3 = xp[3], xv4 = xp[4], xv5 = xp[5];

        float a0 = b1a[0], a1 = b1a[1], a2 = b1a[2], a3 = b1a[3];
        const float4* hp = (const float4*)(h1g + prv * (BB * HH) + b * HH);
        dot64(hp, w10, w11, w12, w13, a0, a1, a2, a3);

        a0 = fmaf(Wx1[ul][0], xv0, a0);      a0 = fmaf(Wx1[ul][1], xv1, a0);
        a0 = fmaf(Wx1[ul][2], xv2, a0);      a0 = fmaf(Wx1[ul][3], xv3, a0);
        a0 = fmaf(Wx1[ul][4], xv4, a0);      a0 = fmaf(Wx1[ul][5], xv5, a0);
        a1 = fmaf(Wx1[4 + ul][0], xv0, a1);  a1 = fmaf(Wx1[4 + ul][1], xv1, a1);
        a1 = fmaf(Wx1[4 + ul][2], xv2, a1);  a1 = fmaf(Wx1[4 + ul][3], xv3, a1);
        a1 = fmaf(Wx1[4 + ul][4], xv4, a1);  a1 = fmaf(Wx1[4 + ul][5], xv5, a1);
        a2 = fmaf(Wx1[8 + ul][0], xv0, a2);  a2 = fmaf(Wx1[8 + ul][1], xv1, a2);
        a2 = fmaf(Wx1[8 + ul][2], xv2, a2);  a2 = fmaf(Wx1[8 + ul][3], xv3, a2);
        a2 = fmaf(Wx1[8 + ul][4], xv4, a2);  a2 = fmaf(Wx1[8 + ul][5], xv5, a2);
        a3 = fmaf(Wx1[12 + ul][0], xv0, a3); a3 = fmaf(Wx1[12 + ul][1], xv1, a3);
        a3 = fmaf(Wx1[12 + ul][2], xv2, a3); a3 = fmaf(Wx1[12 + ul][3], xv3, a3);
        a3 = fmaf(Wx1[12 + ul][4], xv4, a3); a3 = fmaf(Wx1[12 + ul][5], xv5, a3);

        const float i1 = sigf(a0), f1 = sigf(a1);
        const float g1 = tanhf_fast(a2), o1 = sigf(a3);
        c1 = fmaf(f1, c1, i1 * g1);
        const float h1v = o1 * tanhf_fast(c1);
        h1g[cur * (BB * HH) + b * HH + unit] = h1v;

        // publish h1(t); also orders h2(t-1) writes (they precede this arrival)
        group_barrier(flags, bg, t + 1);

        if (t > 0) {
            const float* h2row = h2g + ((t - 1) & 1) * (BB * HH) + ro * HH;
            emit_out(h2row, Wo, redsc, b_out, out + ro * (TT * DDIM) + (t - 1) * DDIM, tid);
        }

        // ---- layer 2: inputs h1(t) and h2(t-1) ----
        float e0 = b2a[0], e1 = b2a[1], e2 = b2a[2], e3 = b2a[3];
        const float4* hp1 = (const float4*)(h1g + cur * (BB * HH) + b * HH);
        const float4* hp2 = (const float4*)(h2g + prv * (BB * HH) + b * HH);
        dot64(hp1, w20, w21, w22, w23, e0, e1, e2, e3);
        dot64(hp2, w20 + 64, w21 + 64, w22 + 64, w23 + 64, e0, e1, e2, e3);

        const float i2 = sigf(e0), f2 = sigf(e1);
        const float g2 = tanhf_fast(e2), o2 = sigf(e3);
        c2 = fmaf(f2, c2, i2 * g2);
        const float h2v = o2 * tanhf_fast(c2);
        h2g[cur * (BB * HH) + b * HH + unit] = h2v;
    }

    group_barrier(flags, bg, TT + 1);
    {
        const float* h2row = h2g + ((TT - 1) & 1) * (BB * HH) + ro * HH;
        emit_out(h2row, Wo, redsc, b_out, out + ro * (TT * DDIM) + (TT - 1) * DDIM, tid);
    }
}

extern "C" void kernel_launch(void* const* d_in, const int* in_sizes, int n_in,
                              void* d_out, int out_size, void* d_ws, size_t ws_size,
                              hipStream_t stream) {
    (void)in_sizes; (void)n_in; (void)out_size; (void)ws_size;
    const float* x     = (const float*)d_in[0];
    const float* W_ih1 = (const float*)d_in[1];
    const float* W_hh1 = (const float*)d_in[2];
    const float* b_ih1 = (const float*)d_in[3];
    const float* b_hh1 = (const float*)d_in[4];
    const float* W_ih2 = (const float*)d_in[5];
    const float* W_hh2 = (const float*)d_in[6];
    const float* b_ih2 = (const float*)d_in[7];
    const float* b_hh2 = (const float*)d_in[8];
    const float* W_out = (const float*)d_in[9];
    const float* b_out = (const float*)d_in[10];
    float* out = (float*)d_out;

    char* ws = (char*)d_ws;
    int*   flags = (int*)ws;                  // 256 * 4 B
    float* h1g   = (float*)(ws + 1024);       // 2*256*256 f32
    float* h2g   = (float*)(ws + 525312);     // 2*256*256 f32

    // zero flags + both h double-buffers every call (replay-safe)
    hipMemsetAsync(d_ws, 0, 1049600, stream);

    hipLaunchKernelGGL(lstm_persist, dim3(256), dim3(256), 0, stream,
                       x, W_ih1, W_hh1, b_ih1, b_hh1,
                       W_ih2, W_hh2, b_ih2, b_hh2,
                       W_out, b_out, out, flags, h1g, h2g);
}

// Round 3
// 18448.096 us; speedup vs baseline: 2.2497x; 2.2497x over previous
//
#include <hip/hip_runtime.h>

#define BB 256
#define TT 1024
#define DDIM 6
#define HH 256
#define AGSCOPE __HIP_MEMORY_SCOPE_AGENT

typedef float f4 __attribute__((ext_vector_type(4)));
typedef float f2 __attribute__((ext_vector_type(2)));

// grid: 256 blocks = 4 batch-groups (bg = blk & 3) x 64 gate-groups (gg = blk >> 2)
// block: 256 threads = 64 batch rows (b_l = tid >> 2) x 4 units (ul = tid & 3)
// ws: flags[256] @0 | h1g[2][256][256] f32 @1024 | h2g[2][256][256] @525312
//
// Exchange protocol (no fences, no inline-asm memory ops):
//   writers: __hip_atomic_store relaxed/agent (sc0 sc1 write-through -> no dirty
//            L2 lines), drained to the coherence point by the vmcnt(0) the
//            compiler emits before s_barrier inside __syncthreads.
//   publish: relaxed agent flag store by tid0 (in-order issue after barrier).
//   consume: 64 lanes poll peer flags relaxed; tid0 then does ONE acquire load
//            (emits buffer_inv: invalidates this CU's L1 + XCD's L2 clean
//            lines) before the closing __syncthreads. All h reads are plain
//            vectorized loads after a barrier-with-invalidate.

__device__ __forceinline__ float sigf(float x) {
    return __builtin_amdgcn_rcpf(1.0f + __expf(-x));
}
__device__ __forceinline__ float tanhf_fast(float x) {
    return fmaf(2.0f, __builtin_amdgcn_rcpf(1.0f + __expf(-2.0f * x)), -1.0f);
}
__device__ __forceinline__ void st_agent(float* p, float v) {
    __hip_atomic_store(p, v, __ATOMIC_RELAXED, AGSCOPE);
}

__device__ __forceinline__ void group_barrier(int* flags, int bg, int token) {
    __syncthreads();                      // drains vmcnt -> h stores visible at L3
    asm volatile("" ::: "memory");        // compile-time: keep flag store below
    if (threadIdx.x == 0) {
        __hip_atomic_store(&flags[blockIdx.x], token, __ATOMIC_RELAXED, AGSCOPE);
    }
    if (threadIdx.x < 64) {
        while (__hip_atomic_load(&flags[bg + 4 * (int)threadIdx.x], __ATOMIC_RELAXED,
                                 AGSCOPE) < token) {
            __builtin_amdgcn_s_sleep(1);
        }
    }
    if (threadIdx.x == 0) {               // one buffer_inv per block per step
        (void)__hip_atomic_load(&flags[blockIdx.x], __ATOMIC_ACQUIRE, AGSCOPE);
    }
    __syncthreads();
    asm volatile("" ::: "memory");        // compile-time: no load hoisting above
}

// 16 h-quads (registers) x 4 LDS weight rows, packed-f32 FMAs.
__device__ __forceinline__ void fma16(const f4 (&hb)[16],
    const f4* __restrict__ w0, const f4* __restrict__ w1,
    const f4* __restrict__ w2, const f4* __restrict__ w3, int kb,
    f2& A0, f2& A1, f2& A2, f2& A3)
{
    #pragma unroll
    for (int j = 0; j < 16; ++j) {
        const f4 h = hb[j];
        const f2 hl = h.xy, hh = h.zw;
        const f4 q0 = w0[kb + j];
        A0 = __builtin_elementwise_fma(hl, q0.xy, A0);
        A0 = __builtin_elementwise_fma(hh, q0.zw, A0);
        const f4 q1 = w1[kb + j];
        A1 = __builtin_elementwise_fma(hl, q1.xy, A1);
        A1 = __builtin_elementwise_fma(hh, q1.zw, A1);
        const f4 q2 = w2[kb + j];
        A2 = __builtin_elementwise_fma(hl, q2.xy, A2);
        A2 = __builtin_elementwise_fma(hh, q2.zw, A2);
        const f4 q3 = w3[kb + j];
        A3 = __builtin_elementwise_fma(hl, q3.xy, A3);
        A3 = __builtin_elementwise_fma(hh, q3.zw, A3);
    }
}

// 256-long dot vs 4 weight rows; plain f4 loads, 4 chunks of 16, two register
// buffers so chunk k+1's loads are in flight while chunk k's FMAs run.
__device__ __forceinline__ void dot256(const f4* __restrict__ hp,
    const f4* __restrict__ w0, const f4* __restrict__ w1,
    const f4* __restrict__ w2, const f4* __restrict__ w3,
    f2& A0, f2& A1, f2& A2, f2& A3)
{
    f4 bufA[16], bufB[16];
    #pragma unroll
    for (int j = 0; j < 16; ++j) bufA[j] = hp[j];
    #pragma unroll
    for (int j = 0; j < 16; ++j) bufB[j] = hp[16 + j];
    fma16(bufA, w0, w1, w2, w3, 0, A0, A1, A2, A3);
    #pragma unroll
    for (int j = 0; j < 16; ++j) bufA[j] = hp[32 + j];
    fma16(bufB, w0, w1, w2, w3, 16, A0, A1, A2, A3);
    #pragma unroll
    for (int j = 0; j < 16; ++j) bufB[j] = hp[48 + j];
    fma16(bufA, w0, w1, w2, w3, 32, A0, A1, A2, A3);
    fma16(bufB, w0, w1, w2, w3, 48, A0, A1, A2, A3);
}

__device__ __forceinline__ void emit_out(const float* __restrict__ h2row,
                                         const float (*Wo)[256],
                                         float (*redsc)[8],
                                         float boV,
                                         float* __restrict__ op, int tid) {
    const float hval = h2row[tid];
    float p0 = Wo[0][tid] * hval;
    float p1 = Wo[1][tid] * hval;
    float p2 = Wo[2][tid] * hval;
    float p3 = Wo[3][tid] * hval;
    float p4 = Wo[4][tid] * hval;
    float p5 = Wo[5][tid] * hval;
    #pragma unroll
    for (int off = 1; off < 64; off <<= 1) {
        p0 += __shfl_xor(p0, off);
        p1 += __shfl_xor(p1, off);
        p2 += __shfl_xor(p2, off);
        p3 += __shfl_xor(p3, off);
        p4 += __shfl_xor(p4, off);
        p5 += __shfl_xor(p5, off);
    }
    const int wid = tid >> 6;
    if ((tid & 63) == 0) {
        redsc[wid][0] = p0; redsc[wid][1] = p1; redsc[wid][2] = p2;
        redsc[wid][3] = p3; redsc[wid][4] = p4; redsc[wid][5] = p5;
    }
    __syncthreads();
    if (tid < 6) {
        op[tid] = redsc[0][tid] + redsc[1][tid] + redsc[2][tid] + redsc[3][tid] + boV;
    }
}

__global__ __launch_bounds__(256, 1) void lstm_persist(
    const float* __restrict__ x,
    const float* __restrict__ W_ih1, const float* __restrict__ W_hh1,
    const float* __restrict__ b_ih1, const float* __restrict__ b_hh1,
    const float* __restrict__ W_ih2, const float* __restrict__ W_hh2,
    const float* __restrict__ b_ih2, const float* __restrict__ b_hh2,
    const float* __restrict__ W_out, const float* __restrict__ b_out,
    float* __restrict__ out,
    int* __restrict__ flags, float* __restrict__ h1g, float* __restrict__ h2g)
{
    __shared__ float L1w[16][260];   // cols 0..255 = W_hh1 row
    __shared__ float Wx1[16][8];     // cols 0..5   = W_ih1 row
    __shared__ float L2w[16][516];   // 0..255 = W_ih2 (h1 in), 256..511 = W_hh2 (h2 in)
    __shared__ float Wo[6][256];
    __shared__ float redsc[4][8];

    const int tid = threadIdx.x;
    const int bg  = blockIdx.x & 3;
    const int gg  = blockIdx.x >> 2;
    const int b_l = tid >> 2;
    const int ul  = tid & 3;
    const int unit = (gg << 2) + ul;
    const int b    = (bg << 6) + b_l;
    const int ro   = (bg << 6) + gg;

    for (int rl = 0; rl < 16; ++rl) {
        const int g  = rl >> 2;
        const int u2 = rl & 3;
        const int gr = g * HH + (gg << 2) + u2;
        L1w[rl][tid]       = W_hh1[gr * HH + tid];
        if (tid < DDIM) Wx1[rl][tid] = W_ih1[gr * DDIM + tid];
        L2w[rl][tid]       = W_ih2[gr * HH + tid];
        L2w[rl][256 + tid] = W_hh2[gr * HH + tid];
    }
    for (int i = tid; i < 6 * 256; i += 256) Wo[i >> 8][i & 255] = W_out[i];

    float b1a[4], b2a[4];
    #pragma unroll
    for (int g = 0; g < 4; ++g) {
        const int gr = g * HH + unit;
        b1a[g] = b_ih1[gr] + b_hh1[gr];
        b2a[g] = b_ih2[gr] + b_hh2[gr];
    }
    const float boV = (tid < 6) ? b_out[tid] : 0.0f;
    __syncthreads();

    const f4* w10 = (const f4*)&L1w[ul][0];
    const f4* w11 = (const f4*)&L1w[4 + ul][0];
    const f4* w12 = (const f4*)&L1w[8 + ul][0];
    const f4* w13 = (const f4*)&L1w[12 + ul][0];
    const f4* w20 = (const f4*)&L2w[ul][0];
    const f4* w21 = (const f4*)&L2w[4 + ul][0];
    const f4* w22 = (const f4*)&L2w[8 + ul][0];
    const f4* w23 = (const f4*)&L2w[12 + ul][0];

    float c1 = 0.0f, c2 = 0.0f;

    #pragma unroll 1
    for (int t = 0; t < TT; ++t) {
        const int cur = t & 1, prv = cur ^ 1;

        // ---- x-part ----
        const float* xp = x + b * (TT * DDIM) + t * DDIM;
        const float xv0 = xp[0], xv1 = xp[1], xv2 = xp[2];
        const float xv3 = xp[3], xv4 = xp[4], xv5 = xp[5];

        float xa0 = b1a[0], xa1 = b1a[1], xa2 = b1a[2], xa3 = b1a[3];
        xa0 = fmaf(Wx1[ul][0], xv0, xa0);      xa0 = fmaf(Wx1[ul][1], xv1, xa0);
        xa0 = fmaf(Wx1[ul][2], xv2, xa0);      xa0 = fmaf(Wx1[ul][3], xv3, xa0);
        xa0 = fmaf(Wx1[ul][4], xv4, xa0);      xa0 = fmaf(Wx1[ul][5], xv5, xa0);
        xa1 = fmaf(Wx1[4 + ul][0], xv0, xa1);  xa1 = fmaf(Wx1[4 + ul][1], xv1, xa1);
        xa1 = fmaf(Wx1[4 + ul][2], xv2, xa1);  xa1 = fmaf(Wx1[4 + ul][3], xv3, xa1);
        xa1 = fmaf(Wx1[4 + ul][4], xv4, xa1);  xa1 = fmaf(Wx1[4 + ul][5], xv5, xa1);
        xa2 = fmaf(Wx1[8 + ul][0], xv0, xa2);  xa2 = fmaf(Wx1[8 + ul][1], xv1, xa2);
        xa2 = fmaf(Wx1[8 + ul][2], xv2, xa2);  xa2 = fmaf(Wx1[8 + ul][3], xv3, xa2);
        xa2 = fmaf(Wx1[8 + ul][4], xv4, xa2);  xa2 = fmaf(Wx1[8 + ul][5], xv5, xa2);
        xa3 = fmaf(Wx1[12 + ul][0], xv0, xa3); xa3 = fmaf(Wx1[12 + ul][1], xv1, xa3);
        xa3 = fmaf(Wx1[12 + ul][2], xv2, xa3); xa3 = fmaf(Wx1[12 + ul][3], xv3, xa3);
        xa3 = fmaf(Wx1[12 + ul][4], xv4, xa3); xa3 = fmaf(Wx1[12 + ul][5], xv5, xa3);

        // ---- layer 1 h-dot ----
        f2 A0 = {0.f, 0.f}, A1 = {0.f, 0.f}, A2 = {0.f, 0.f}, A3 = {0.f, 0.f};
        const f4* hp = (const f4*)(h1g + prv * (BB * HH) + b * HH);
        dot256(hp, w10, w11, w12, w13, A0, A1, A2, A3);

        const float i1 = sigf(xa0 + A0.x + A0.y);
        const float f1 = sigf(xa1 + A1.x + A1.y);
        const float g1 = tanhf_fast(xa2 + A2.x + A2.y);
        const float o1 = sigf(xa3 + A3.x + A3.y);
        c1 = fmaf(f1, c1, i1 * g1);
        const float h1v = o1 * tanhf_fast(c1);
        st_agent(&h1g[cur * (BB * HH) + b * HH + unit], h1v);

        // publish h1(t); h2(t-1) stores (pre-arrival) publish too
        group_barrier(flags, bg, t + 1);

        // ---- layer 2: h1(t) and h2(t-1) ----
        f2 E0 = {0.f, 0.f}, E1 = {0.f, 0.f}, E2 = {0.f, 0.f}, E3 = {0.f, 0.f};
        const f4* hp1 = (const f4*)(h1g + cur * (BB * HH) + b * HH);
        const f4* hp2 = (const f4*)(h2g + prv * (BB * HH) + b * HH);
        dot256(hp1, w20, w21, w22, w23, E0, E1, E2, E3);
        dot256(hp2, w20 + 64, w21 + 64, w22 + 64, w23 + 64, E0, E1, E2, E3);

        const float i2 = sigf(b2a[0] + E0.x + E0.y);
        const float f2v = sigf(b2a[1] + E1.x + E1.y);
        const float g2 = tanhf_fast(b2a[2] + E2.x + E2.y);
        const float o2 = sigf(b2a[3] + E3.x + E3.y);
        c2 = fmaf(f2v, c2, i2 * g2);
        const float h2v = o2 * tanhf_fast(c2);
        st_agent(&h2g[cur * (BB * HH) + b * HH + unit], h2v);

        // out(t-1) from h2(t-1) (published at this step's barrier)
        if (t > 0) {
            const float* h2row = h2g + ((t - 1) & 1) * (BB * HH) + ro * HH;
            emit_out(h2row, Wo, redsc, boV, out + ro * (TT * DDIM) + (t - 1) * DDIM, tid);
        }
    }

    group_barrier(flags, bg, TT + 1);
    {
        const float* h2row = h2g + ((TT - 1) & 1) * (BB * HH) + ro * HH;
        emit_out(h2row, Wo, redsc, boV, out + ro * (TT * DDIM) + (TT - 1) * DDIM, tid);
    }
}

extern "C" void kernel_launch(void* const* d_in, const int* in_sizes, int n_in,
                              void* d_out, int out_size, void* d_ws, size_t ws_size,
                              hipStream_t stream) {
    (void)in_sizes; (void)n_in; (void)out_size; (void)ws_size;
    const float* x     = (const float*)d_in[0];
    const float* W_ih1 = (const float*)d_in[1];
    const float* W_hh1 = (const float*)d_in[2];
    const float* b_ih1 = (const float*)d_in[3];
    const float* b_hh1 = (const float*)d_in[4];
    const float* W_ih2 = (const float*)d_in[5];
    const float* W_hh2 = (const float*)d_in[6];
    const float* b_ih2 = (const float*)d_in[7];
    const float* b_hh2 = (const float*)d_in[8];
    const float* W_out = (const float*)d_in[9];
    const float* b_out = (const float*)d_in[10];
    float* out = (float*)d_out;

    char* ws = (char*)d_ws;
    int*   flags = (int*)ws;                  // 256 * 4 B
    float* h1g   = (float*)(ws + 1024);       // 2*256*256 f32
    float* h2g   = (float*)(ws + 525312);     // 2*256*256 f32

    hipMemsetAsync(d_ws, 0, 1049600, stream);

    hipLaunchKernelGGL(lstm_persist, dim3(256), dim3(256), 0, stream,
                       x, W_ih1, W_hh1, b_ih1, b_hh1,
                       W_ih2, W_hh2, b_ih2, b_hh2,
                       W_out, b_out, out, flags, h1g, h2g);
}

// Round 4
// 17860.606 us; speedup vs baseline: 2.3237x; 1.0329x over previous
//
#include <hip/hip_runtime.h>

#define BB 256
#define TT 1024
#define DDIM 6
#define HH 256
#define AGSCOPE __HIP_MEMORY_SCOPE_AGENT

typedef float f4 __attribute__((ext_vector_type(4)));
typedef float f2 __attribute__((ext_vector_type(2)));

// grid: 256 blocks = 8 batch-groups (bg = blk & 7) x 32 unit-groups (gg = blk >> 3)
//   batch-group bg owns batch rows [bg*32, bg*32+32); its 32 WGs likely share
//   one XCD (round-robin dispatch) -> h lines refill L2 once, 31 hits.
// block: 256 threads = 32 batch rows (b_l = tid >> 3) x 8 units (ul = tid & 7)
// ws: flags[256] @0 | h1g[2][256][256] f32 @1024 | h2g[2][256][256] @525312
//
// Exchange protocol (R3-proven): writers relaxed-agent stores (write-through,
// drained by the vmcnt(0) before s_barrier in __syncthreads); publish = relaxed
// flag store; consume = poll + ONE acquire load (buffer_inv) per WG per step;
// all h reads are plain vectorized loads after the barrier-with-invalidate.

__device__ __forceinline__ float sigf(float x) {
    return __builtin_amdgcn_rcpf(1.0f + __expf(-x));
}
__device__ __forceinline__ float tanhf_fast(float x) {
    return fmaf(2.0f, __builtin_amdgcn_rcpf(1.0f + __expf(-2.0f * x)), -1.0f);
}
__device__ __forceinline__ void st_agent(float* p, float v) {
    __hip_atomic_store(p, v, __ATOMIC_RELAXED, AGSCOPE);
}

__device__ __forceinline__ void group_barrier(int* flags, int bg, int token) {
    __syncthreads();                      // drains vmcnt -> h stores at L3
    asm volatile("" ::: "memory");
    if (threadIdx.x == 0) {
        __hip_atomic_store(&flags[blockIdx.x], token, __ATOMIC_RELAXED, AGSCOPE);
    }
    if (threadIdx.x < 32) {               // poll the 32 peers of this group
        while (__hip_atomic_load(&flags[bg + 8 * (int)threadIdx.x], __ATOMIC_RELAXED,
                                 AGSCOPE) < token) {
            __builtin_amdgcn_s_sleep(2);
        }
    }
    if (threadIdx.x == 0) {               // one buffer_inv per block per step
        (void)__hip_atomic_load(&flags[blockIdx.x], __ATOMIC_ACQUIRE, AGSCOPE);
    }
    __syncthreads();
    asm volatile("" ::: "memory");
}

// 16 h-quads (registers) x 4 LDS weight rows, packed-f32 FMAs.
__device__ __forceinline__ void fma16(const f4 (&hb)[16],
    const f4* __restrict__ w0, const f4* __restrict__ w1,
    const f4* __restrict__ w2, const f4* __restrict__ w3, int kb,
    f2& A0, f2& A1, f2& A2, f2& A3)
{
    #pragma unroll
    for (int j = 0; j < 16; ++j) {
        const f4 h = hb[j];
        const f2 hl = h.xy, hh = h.zw;
        const f4 q0 = w0[kb + j];
        A0 = __builtin_elementwise_fma(hl, q0.xy, A0);
        A0 = __builtin_elementwise_fma(hh, q0.zw, A0);
        const f4 q1 = w1[kb + j];
        A1 = __builtin_elementwise_fma(hl, q1.xy, A1);
        A1 = __builtin_elementwise_fma(hh, q1.zw, A1);
        const f4 q2 = w2[kb + j];
        A2 = __builtin_elementwise_fma(hl, q2.xy, A2);
        A2 = __builtin_elementwise_fma(hh, q2.zw, A2);
        const f4 q3 = w3[kb + j];
        A3 = __builtin_elementwise_fma(hl, q3.xy, A3);
        A3 = __builtin_elementwise_fma(hh, q3.zw, A3);
    }
}

// 256-long dot vs 4 weight rows; plain f4 loads, 4 chunks of 16, two register
// buffers so chunk k+1's loads are in flight while chunk k's FMAs run.
__device__ __forceinline__ void dot256(const f4* __restrict__ hp,
    const f4* __restrict__ w0, const f4* __restrict__ w1,
    const f4* __restrict__ w2, const f4* __restrict__ w3,
    f2& A0, f2& A1, f2& A2, f2& A3)
{
    f4 bufA[16], bufB[16];
    #pragma unroll
    for (int j = 0; j < 16; ++j) bufA[j] = hp[j];
    #pragma unroll
    for (int j = 0; j < 16; ++j) bufB[j] = hp[16 + j];
    fma16(bufA, w0, w1, w2, w3, 0, A0, A1, A2, A3);
    #pragma unroll
    for (int j = 0; j < 16; ++j) bufA[j] = hp[32 + j];
    fma16(bufB, w0, w1, w2, w3, 16, A0, A1, A2, A3);
    #pragma unroll
    for (int j = 0; j < 16; ++j) bufB[j] = hp[48 + j];
    fma16(bufA, w0, w1, w2, w3, 32, A0, A1, A2, A3);
    fma16(bufB, w0, w1, w2, w3, 48, A0, A1, A2, A3);
}

__device__ __forceinline__ void emit_out(const float* __restrict__ h2row,
                                         const float (*Wo)[256],
                                         float (*redsc)[8],
                                         float boV,
                                         float* __restrict__ op, int tid) {
    const float hval = h2row[tid];
    float p0 = Wo[0][tid] * hval;
    float p1 = Wo[1][tid] * hval;
    float p2 = Wo[2][tid] * hval;
    float p3 = Wo[3][tid] * hval;
    float p4 = Wo[4][tid] * hval;
    float p5 = Wo[5][tid] * hval;
    #pragma unroll
    for (int off = 1; off < 64; off <<= 1) {
        p0 += __shfl_xor(p0, off);
        p1 += __shfl_xor(p1, off);
        p2 += __shfl_xor(p2, off);
        p3 += __shfl_xor(p3, off);
        p4 += __shfl_xor(p4, off);
        p5 += __shfl_xor(p5, off);
    }
    const int wid = tid >> 6;
    if ((tid & 63) == 0) {
        redsc[wid][0] = p0; redsc[wid][1] = p1; redsc[wid][2] = p2;
        redsc[wid][3] = p3; redsc[wid][4] = p4; redsc[wid][5] = p5;
    }
    __syncthreads();
    if (tid < 6) {
        op[tid] = redsc[0][tid] + redsc[1][tid] + redsc[2][tid] + redsc[3][tid] + boV;
    }
}

__global__ __launch_bounds__(256, 1) void lstm_persist(
    const float* __restrict__ x,
    const float* __restrict__ W_ih1, const float* __restrict__ W_hh1,
    const float* __restrict__ b_ih1, const float* __restrict__ b_hh1,
    const float* __restrict__ W_ih2, const float* __restrict__ W_hh2,
    const float* __restrict__ b_ih2, const float* __restrict__ b_hh2,
    const float* __restrict__ W_out, const float* __restrict__ b_out,
    float* __restrict__ out,
    int* __restrict__ flags, float* __restrict__ h1g, float* __restrict__ h2g)
{
    // 32 gate rows/WG (4 gates x 8 units). Row strides 260/516 (mod 32 = 4):
    // lanes ul=0..7 hit disjoint bank-quads 4*ul; same-address 8-lane
    // broadcasts are free.
    __shared__ float L1w[32][260];   // cols 0..255 = W_hh1 row
    __shared__ float Wx1[32][8];     // cols 0..5   = W_ih1 row
    __shared__ float L2w[32][516];   // 0..255 = W_ih2 (h1 in), 256..511 = W_hh2 (h2 in)
    __shared__ float Wo[6][256];
    __shared__ float redsc[4][8];

    const int tid = threadIdx.x;
    const int bg  = blockIdx.x & 7;        // batch-group (likely one XCD)
    const int gg  = blockIdx.x >> 3;       // unit-group
    const int b_l = tid >> 3;
    const int ul  = tid & 7;
    const int unit = (gg << 3) + ul;       // hidden unit this thread owns
    const int b    = (bg << 5) + b_l;      // global batch row
    const int ro   = (bg << 5) + gg;       // batch row whose `out` this WG emits

    for (int rl = 0; rl < 32; ++rl) {
        const int g  = rl >> 3;
        const int u2 = rl & 7;
        const int gr = g * HH + (gg << 3) + u2;   // global gate row
        L1w[rl][tid]       = W_hh1[gr * HH + tid];
        if (tid < DDIM) Wx1[rl][tid] = W_ih1[gr * DDIM + tid];
        L2w[rl][tid]       = W_ih2[gr * HH + tid];
        L2w[rl][256 + tid] = W_hh2[gr * HH + tid];
    }
    for (int i = tid; i < 6 * 256; i += 256) Wo[i >> 8][i & 255] = W_out[i];

    float b1a[4], b2a[4];
    #pragma unroll
    for (int g = 0; g < 4; ++g) {
        const int gr = g * HH + unit;
        b1a[g] = b_ih1[gr] + b_hh1[gr];
        b2a[g] = b_ih2[gr] + b_hh2[gr];
    }
    const float boV = (tid < 6) ? b_out[tid] : 0.0f;
    __syncthreads();

    const f4* w10 = (const f4*)&L1w[ul][0];
    const f4* w11 = (const f4*)&L1w[8 + ul][0];
    const f4* w12 = (const f4*)&L1w[16 + ul][0];
    const f4* w13 = (const f4*)&L1w[24 + ul][0];
    const f4* w20 = (const f4*)&L2w[ul][0];
    const f4* w21 = (const f4*)&L2w[8 + ul][0];
    const f4* w22 = (const f4*)&L2w[16 + ul][0];
    const f4* w23 = (const f4*)&L2w[24 + ul][0];

    float c1 = 0.0f, c2 = 0.0f;

    #pragma unroll 1
    for (int t = 0; t < TT; ++t) {
        const int cur = t & 1, prv = cur ^ 1;

        // ---- x-part ----
        const float* xp = x + b * (TT * DDIM) + t * DDIM;
        const float xv0 = xp[0], xv1 = xp[1], xv2 = xp[2];
        const float xv3 = xp[3], xv4 = xp[4], xv5 = xp[5];

        float xa0 = b1a[0], xa1 = b1a[1], xa2 = b1a[2], xa3 = b1a[3];
        xa0 = fmaf(Wx1[ul][0], xv0, xa0);      xa0 = fmaf(Wx1[ul][1], xv1, xa0);
        xa0 = fmaf(Wx1[ul][2], xv2, xa0);      xa0 = fmaf(Wx1[ul][3], xv3, xa0);
        xa0 = fmaf(Wx1[ul][4], xv4, xa0);      xa0 = fmaf(Wx1[ul][5], xv5, xa0);
        xa1 = fmaf(Wx1[8 + ul][0], xv0, xa1);  xa1 = fmaf(Wx1[8 + ul][1], xv1, xa1);
        xa1 = fmaf(Wx1[8 + ul][2], xv2, xa1);  xa1 = fmaf(Wx1[8 + ul][3], xv3, xa1);
        xa1 = fmaf(Wx1[8 + ul][4], xv4, xa1);  xa1 = fmaf(Wx1[8 + ul][5], xv5, xa1);
        xa2 = fmaf(Wx1[16 + ul][0], xv0, xa2); xa2 = fmaf(Wx1[16 + ul][1], xv1, xa2);
        xa2 = fmaf(Wx1[16 + ul][2], xv2, xa2); xa2 = fmaf(Wx1[16 + ul][3], xv3, xa2);
        xa2 = fmaf(Wx1[16 + ul][4], xv4, xa2); xa2 = fmaf(Wx1[16 + ul][5], xv5, xa2);
        xa3 = fmaf(Wx1[24 + ul][0], xv0, xa3); xa3 = fmaf(Wx1[24 + ul][1], xv1, xa3);
        xa3 = fmaf(Wx1[24 + ul][2], xv2, xa3); xa3 = fmaf(Wx1[24 + ul][3], xv3, xa3);
        xa3 = fmaf(Wx1[24 + ul][4], xv4, xa3); xa3 = fmaf(Wx1[24 + ul][5], xv5, xa3);

        // ---- layer 1 h-dot ----
        f2 A0 = {0.f, 0.f}, A1 = {0.f, 0.f}, A2 = {0.f, 0.f}, A3 = {0.f, 0.f};
        const f4* hp = (const f4*)(h1g + prv * (BB * HH) + b * HH);
        dot256(hp, w10, w11, w12, w13, A0, A1, A2, A3);

        const float i1 = sigf(xa0 + A0.x + A0.y);
        const float f1 = sigf(xa1 + A1.x + A1.y);
        const float g1 = tanhf_fast(xa2 + A2.x + A2.y);
        const float o1 = sigf(xa3 + A3.x + A3.y);
        c1 = fmaf(f1, c1, i1 * g1);
        const float h1v = o1 * tanhf_fast(c1);
        st_agent(&h1g[cur * (BB * HH) + b * HH + unit], h1v);

        // publish h1(t); h2(t-1) stores (pre-arrival) publish too
        group_barrier(flags, bg, t + 1);

        // ---- layer 2: h1(t) and h2(t-1) ----
        f2 E0 = {0.f, 0.f}, E1 = {0.f, 0.f}, E2 = {0.f, 0.f}, E3 = {0.f, 0.f};
        const f4* hp1 = (const f4*)(h1g + cur * (BB * HH) + b * HH);
        const f4* hp2 = (const f4*)(h2g + prv * (BB * HH) + b * HH);
        dot256(hp1, w20, w21, w22, w23, E0, E1, E2, E3);
        dot256(hp2, w20 + 64, w21 + 64, w22 + 64, w23 + 64, E0, E1, E2, E3);

        const float i2 = sigf(b2a[0] + E0.x + E0.y);
        const float f2v = sigf(b2a[1] + E1.x + E1.y);
        const float g2 = tanhf_fast(b2a[2] + E2.x + E2.y);
        const float o2 = sigf(b2a[3] + E3.x + E3.y);
        c2 = fmaf(f2v, c2, i2 * g2);
        const float h2v = o2 * tanhf_fast(c2);
        st_agent(&h2g[cur * (BB * HH) + b * HH + unit], h2v);

        // out(t-1) from h2(t-1) (published at this step's barrier; L2-hot —
        // hp2 just read the same buffer)
        if (t > 0) {
            const float* h2row = h2g + ((t - 1) & 1) * (BB * HH) + ro * HH;
            emit_out(h2row, Wo, redsc, boV, out + ro * (TT * DDIM) + (t - 1) * DDIM, tid);
        }
    }

    group_barrier(flags, bg, TT + 1);
    {
        const float* h2row = h2g + ((TT - 1) & 1) * (BB * HH) + ro * HH;
        emit_out(h2row, Wo, redsc, boV, out + ro * (TT * DDIM) + (TT - 1) * DDIM, tid);
    }
}

extern "C" void kernel_launch(void* const* d_in, const int* in_sizes, int n_in,
                              void* d_out, int out_size, void* d_ws, size_t ws_size,
                              hipStream_t stream) {
    (void)in_sizes; (void)n_in; (void)out_size; (void)ws_size;
    const float* x     = (const float*)d_in[0];
    const float* W_ih1 = (const float*)d_in[1];
    const float* W_hh1 = (const float*)d_in[2];
    const float* b_ih1 = (const float*)d_in[3];
    const float* b_hh1 = (const float*)d_in[4];
    const float* W_ih2 = (const float*)d_in[5];
    const float* W_hh2 = (const float*)d_in[6];
    const float* b_ih2 = (const float*)d_in[7];
    const float* b_hh2 = (const float*)d_in[8];
    const float* W_out = (const float*)d_in[9];
    const float* b_out = (const float*)d_in[10];
    float* out = (float*)d_out;

    char* ws = (char*)d_ws;
    int*   flags = (int*)ws;                  // 256 * 4 B
    float* h1g   = (float*)(ws + 1024);       // 2*256*256 f32
    float* h2g   = (float*)(ws + 525312);     // 2*256*256 f32

    hipMemsetAsync(d_ws, 0, 1049600, stream);

    hipLaunchKernelGGL(lstm_persist, dim3(256), dim3(256), 0, stream,
                       x, W_ih1, W_hh1, b_ih1, b_hh1,
                       W_ih2, W_hh2, b_ih2, b_hh2,
                       W_out, b_out, out, flags, h1g, h2g);
}